// Round 8
// baseline (220.381 us; speedup 1.0000x reference)
//
#include <hip/hip_runtime.h>
#include <stdint.h>

typedef unsigned short u16;

#define MTOK 4096
#define CIN  3072
#define COUT 3072
#define RANK 32
#define RS   3136       // row stride for xdq/wdq (6272 B: gcd with 4096 = 128 -> good HBM channel spread)
#define LKSPLIT 16
#define LKC (CIN/LKSPLIT)   // 192 = 3 k-tiles
#define WROWS 6             // wdq rows per prep block (3072 / 512)

typedef __attribute__((ext_vector_type(8))) short bf16x8;
typedef __attribute__((ext_vector_type(4))) float f32x4;

__device__ __forceinline__ u16 f2bf(float f) {
  union { float f; unsigned u; } v; v.f = f;
  unsigned r = v.u + 0x7FFFu + ((v.u >> 16) & 1u);  // RNE
  return (u16)(r >> 16);
}

__device__ __forceinline__ void gload_lds16(const void* g, void* l) {
  __builtin_amdgcn_global_load_lds(
      (const __attribute__((address_space(1))) unsigned int*)g,
      (__attribute__((address_space(3))) unsigned int*)l, 16, 0, 0);
}

__device__ __forceinline__ float quant1(float xs, float ascale, float qd) {
  float q = rintf(xs / qd);                      // jnp.round = RNE, exact IEEE div
  q = fminf(fmaxf(q, -8.f), 7.f);
  return q * ascale;
}

// Prep (R5 uniform version, kept): 512 uniform blocks; each does 6 wdq rows +
// one lora/quant panel. Five prep structures measured identical totals —
// prep is NOT the bottleneck; leave it alone.
__global__ __launch_bounds__(256) void prep_kernel(
    const float* __restrict__ x, const float* __restrict__ smooth,
    const int* __restrict__ qw, const float* __restrict__ wsc,
    const float* __restrict__ pd, const float* __restrict__ pu,
    u16* __restrict__ xdq, u16* __restrict__ wdq, u16* __restrict__ pu_bf,
    float* __restrict__ lp)
{
  const int b = blockIdx.x;      // 0..511
  const int t = threadIdx.x;

#pragma unroll
  for (int r = 0; r < WROWS; ++r) {
    const int o = b * WROWS + r;
    const int4* qrow = (const int4*)(qw + (size_t)o * CIN);
    u16* orow = wdq + (size_t)o * RS;
#pragma unroll
    for (int p = 0; p < 3; ++p) {
      const int c4 = p * 256 + t;
      const int g = (c4 * 4) >> 6;
      const float ws = wsc[g * COUT + o];    // wscales is (G, C_out)
      const int4 qv = qrow[c4];
      ushort4 ov;
      ov.x = f2bf((float)(qv.x - 8) * ws);
      ov.y = f2bf((float)(qv.y - 8) * ws);
      ov.z = f2bf((float)(qv.z - 8) * ws);
      ov.w = f2bf((float)(qv.w - 8) * ws);
      ((ushort4*)orow)[c4] = ov;
    }
  }
  if (t < WROWS * RANK) {
    const int o = b * WROWS + (t >> 5);
    pu_bf[(size_t)o * RANK + (t & 31)] = f2bf(pu[(size_t)o * RANK + (t & 31)]);
  }

  __shared__ __align__(16) u16 sA[128 * 64];
  __shared__ __align__(16) u16 sB[32 * 64];
  const int m0 = (b >> 4) * 128;        // 32 m-panels
  const int kblk = b & 15;              // 16 K-splits
  const int wave = t >> 6, lane = t & 63;
  const int lm = lane & 15, lkq = (lane >> 4) * 8;

  f32x4 acc[2][2];
  const f32x4 fz = {0.f, 0.f, 0.f, 0.f};
#pragma unroll
  for (int i = 0; i < 2; ++i)
#pragma unroll
    for (int j = 0; j < 2; ++j) acc[i][j] = fz;

  for (int kt = 0; kt < LKC / 64; ++kt) {
    const int k0 = kblk * LKC + kt * 64;
    const int col = (t & 15) * 4;       // 16 lanes x 4 = one 64-quant-group per row
#pragma unroll
    for (int it = 0; it < 8; ++it) {
      const int row = it * 16 + (t >> 4);
      const float4 xv = *(const float4*)(x + (size_t)(m0 + row) * CIN + k0 + col);
      const float4 sv = *(const float4*)(smooth + k0 + col);
      const float xs0 = xv.x / sv.x, xs1 = xv.y / sv.y;
      const float xs2 = xv.z / sv.z, xs3 = xv.w / sv.w;
      ushort4 ov;
      ov.x = f2bf(xs0); ov.y = f2bf(xs1); ov.z = f2bf(xs2); ov.w = f2bf(xs3);
      *(ushort4*)&sA[row * 64 + col] = ov;
      float a = fmaxf(fmaxf(fabsf(xs0), fabsf(xs1)), fmaxf(fabsf(xs2), fabsf(xs3)));
#pragma unroll
      for (int off = 1; off < 16; off <<= 1) a = fmaxf(a, __shfl_xor(a, off));
      const float ascale = a / 7.0f;
      const float qd = fmaxf(ascale, 1e-8f);
      ushort4 oq;
      oq.x = f2bf(quant1(xs0, ascale, qd));
      oq.y = f2bf(quant1(xs1, ascale, qd));
      oq.z = f2bf(quant1(xs2, ascale, qd));
      oq.w = f2bf(quant1(xs3, ascale, qd));
      *(ushort4*)(xdq + (size_t)(m0 + row) * RS + k0 + col) = oq;
    }
#pragma unroll
    for (int i = 0; i < 8; ++i) {
      const int idx = i * 256 + t;
      const int k = idx >> 5, r = idx & 31;
      sB[r * 64 + k] = f2bf(pd[(size_t)(k0 + k) * RANK + r]);
    }
    __syncthreads();
#pragma unroll
    for (int kk = 0; kk < 2; ++kk) {
      const int ko = kk * 32 + lkq;
      bf16x8 af[2], bfr[2];
#pragma unroll
      for (int i = 0; i < 2; ++i)
        af[i] = *(const bf16x8*)&sA[(wave * 32 + i * 16 + lm) * 64 + ko];
#pragma unroll
      for (int j = 0; j < 2; ++j)
        bfr[j] = *(const bf16x8*)&sB[(j * 16 + lm) * 64 + ko];
#pragma unroll
      for (int i = 0; i < 2; ++i)
#pragma unroll
        for (int j = 0; j < 2; ++j)
          acc[i][j] = __builtin_amdgcn_mfma_f32_16x16x32_bf16(af[i], bfr[j], acc[i][j], 0, 0, 0);
    }
    __syncthreads();
  }
  float* lpk = lp + (size_t)kblk * MTOK * RANK;
#pragma unroll
  for (int i = 0; i < 2; ++i)
#pragma unroll
    for (int j = 0; j < 2; ++j) {
      const int col = j * 16 + lm;
      const int row0 = m0 + wave * 32 + i * 16 + (lane >> 4) * 4;
#pragma unroll
      for (int r = 0; r < 4; ++r)
        lpk[(size_t)(row0 + r) * RANK + col] = acc[i][j][r];
    }
}

// Reduce lora K-split partials -> bf16 lora_bf (M, 32).
__global__ __launch_bounds__(256) void lora_fix_kernel(
    const float* __restrict__ lp, u16* __restrict__ lora_bf)
{
  const int idx = blockIdx.x * 256 + threadIdx.x;   // MTOK*RANK
  const int m = idx >> 5, c = idx & 31;
  float s = 0.f;
#pragma unroll
  for (int k = 0; k < LKSPLIT; ++k) s += lp[((size_t)k * MTOK + m) * RANK + c];
  lora_bf[(size_t)m * RANK + c] = f2bf(s);
}

// ---------------------------------------------------------------------------
// Main GEMM (R8): 256x192 tile, grid 256 (1/CU), 8 waves (4M x 2N) — R7
// geometry kept — but the K-loop is restructured from {2-buf, 4 phases, 8
// barriers/tile, lgkmcnt(0) before every MFMA burst} to {3-buf rotation,
// BK=32, ONE barrier per tile, reads pipelined under MFMAs}.
//
// Why: R7 measured 4100 cy/tile vs an LDS-server floor of ~1920 cy (160
// ds_read_b128 x 12 cy/CU) — the per-phase lgkmcnt(0) drains serialized the
// LDS pipe against the MFMA pipe. With 3 buffers, stage T+2 targets buf
// (T+2)%3, disjoint from the buffer being read (T%3) AND the next (T+1)%3,
// so no intra-tile barrier is needed and the compiler's counted lgkmcnt lets
// ds_reads run under MFMAs (plus cross-wave overlap at 2 waves/SIMD).
//
// Per tile: [stage T+2: 3-4 gloads] [10 ds_read_b128] [24 MFMA]
//           [lgkmcnt(0)] [vmcnt(n)] [s_barrier]
//  - lgkmcnt(0) before the barrier: a straggling tile-T read must complete
//    before any wave can start stage T+2' (next tile) into buf (T-1)%3...
//    i.e., reads of buf X must drain before the barrier that releases the
//    stage overwriting X (2 tiles later). One wait per tile, nearly free.
//  - vmcnt(n): n = loads this wave issues per tile (waves 0-3: 3, waves
//    4-7: 4 — wave-uniform branch; barrier OUTSIDE the branch). Forces tile
//    T+1's stages complete, leaves T+2's in flight. Never 0 mid-loop.
//
// Bank swizzle at BK=32 (64-B rows = half a 32-bank wrap): conflict granule
// = (row&1, 16B-slot). Frag rows span lm = 16 consecutive rows ->
// slot' = slot ^ ((row>>1)&3) enumerates all 8 granules x 2 lanes = free.
// (R4's 7e6-conflict failure used the SAME formula but 32-lane frag rows
// (32x32 MFMA) -> 4-way; with 16x16 MFMA it is conflict-free. R7's BK=64
// row&7 result is the same theory at full-wrap rows.) Involution applied to
// the stage SOURCE col-chunk; LDS dest stays linear (global_load_lds rule).
//
// K order per acc element: one MFMA per 32-K tile, tiles ascending — same
// K-slice sequence as R7's (kt, kk) -> BIT-IDENTICAL output.
// LDS: A 3x16KB (base 0, buf*8192 u16) + B 3x12KB (base 24576, buf*6144)
//      = 84 KB.
// ---------------------------------------------------------------------------

__device__ __forceinline__ void stage32(const u16* __restrict__ Ag,
                                        const u16* __restrict__ Bg,
                                        u16* lds, int kt, int buf,
                                        int t, int wid) {
  // A: 256 rows x 32 cols = 1024 16B-chunks, 2 per thread
#pragma unroll
  for (int r = 0; r < 2; ++r) {
    const int id = r * 512 + t;
    const int row = id >> 2, sl = id & 3;
    const int c16 = sl ^ ((row >> 1) & 3);     // source col-chunk (involution)
    gload_lds16(Ag + (size_t)row * RS + kt * 32 + c16 * 8,
                lds + buf * 8192 + id * 8);
  }
  // B: 192 rows x 32 cols = 768 chunks: all threads 1; waves 4-7 a 2nd.
  {
    const int row = t >> 2, sl = t & 3;
    const int c16 = sl ^ ((row >> 1) & 3);
    gload_lds16(Bg + (size_t)row * RS + kt * 32 + c16 * 8,
                lds + 24576 + buf * 6144 + t * 8);
  }
  if (wid >= 4) {                              // wave-uniform
    const int c = 256 + t;                     // t in [256,512) -> c in [512,768)
    const int row = c >> 2, sl = c & 3;
    const int c16 = sl ^ ((row >> 1) & 3);
    gload_lds16(Bg + (size_t)row * RS + kt * 32 + c16 * 8,
                lds + 24576 + buf * 6144 + c * 8);
  }
}

#define RD_ALL(BUF) \
  _Pragma("unroll") for (int a_ = 0; a_ < 4; ++a_) { \
    const int rl = (a_ >> 1) * 128 + wm * 32 + (a_ & 1) * 16 + lm; \
    aF[a_] = *(const bf16x8*)&lds[(BUF) * 8192 + rl * 32 + \
                                  ((q4 ^ ((rl >> 1) & 3)) << 3)]; \
  } \
  _Pragma("unroll") for (int b_ = 0; b_ < 6; ++b_) { \
    const int rb = (b_ / 3) * 96 + wn * 48 + (b_ % 3) * 16 + lm; \
    bF[b_] = *(const bf16x8*)&lds[24576 + (BUF) * 6144 + rb * 32 + \
                                  ((q4 ^ ((rb >> 1) & 3)) << 3)]; \
  }

#define MFMA_ALL() \
  __builtin_amdgcn_s_setprio(1); \
  _Pragma("unroll") for (int a_ = 0; a_ < 4; ++a_) \
  _Pragma("unroll") for (int b_ = 0; b_ < 6; ++b_) \
    acc[a_][b_] = __builtin_amdgcn_mfma_f32_16x16x32_bf16( \
        aF[a_], bF[b_], acc[a_][b_], 0, 0, 0); \
  __builtin_amdgcn_s_setprio(0);

// Boundary wait: per-wave staged-loads count (3 for waves 0-3, 4 for 4-7).
#define VMB() do { \
  if (wid < 4) asm volatile("s_waitcnt vmcnt(3)" ::: "memory"); \
  else         asm volatile("s_waitcnt vmcnt(4)" ::: "memory"); \
} while (0)
#define VM0() asm volatile("s_waitcnt vmcnt(0)" ::: "memory")
#define LK0() asm volatile("s_waitcnt lgkmcnt(0)" ::: "memory")

// One K-tile. CB = buf (compile-time), SB = stage buf, KT2 = tile to stage.
#define TILE3(CB, SB, KT2, DOSTAGE, VMW, DOBAR) do { \
  if (DOSTAGE) stage32(Ag, Bg, lds, (KT2), (SB), t, wid); \
  RD_ALL(CB); \
  MFMA_ALL(); \
  LK0(); \
  VMW; \
  if (DOBAR) { \
    __builtin_amdgcn_s_barrier(); \
    __builtin_amdgcn_sched_barrier(0); \
  } \
} while (0)

__global__ __launch_bounds__(512, 2) void gemm_kernel(
    const u16* __restrict__ xdq, const u16* __restrict__ wdq,
    const u16* __restrict__ pu_bf, const u16* __restrict__ lora_bf,
    const float* __restrict__ bias, float* __restrict__ out)
{
  __shared__ __align__(16) u16 lds[43008];   // 84 KiB: A 3x8192, B base 24576 3x6144

  const int t = threadIdx.x;
  const int wid = t >> 6, lane = t & 63;
  const int wm = wid >> 1, wn = wid & 1;     // 4M x 2N wave grid
  const int lm = lane & 15, q4 = lane >> 4;

  // XCD swizzle: 256 = 8 XCDs x 32; each XCD gets 2 full M-rows of tiles.
  const int wg = blockIdx.x;
  const int swz = (wg & 7) * 32 + (wg >> 3);
  const int by = swz >> 4, bx = swz & 15;    // 16 x 16 tile grid
  const int m0 = by * 256, n0 = bx * 192;

  const u16* Ag = xdq + (size_t)m0 * RS;
  const u16* Bg = wdq + (size_t)n0 * RS;

  f32x4 acc[4][6];
  const f32x4 fz = {0.f, 0.f, 0.f, 0.f};
#pragma unroll
  for (int i = 0; i < 4; ++i)
#pragma unroll
    for (int j = 0; j < 6; ++j) acc[i][j] = fz;

  bf16x8 aF[4], bF[6];

  // Prologue: stage tile 0 -> buf0, tile 1 -> buf1; force tile 0 (leave 1's
  // loads in flight); barrier.
  stage32(Ag, Bg, lds, 0, 0, t, wid);
  stage32(Ag, Bg, lds, 1, 1, t, wid);
  VMB();
  __builtin_amdgcn_s_barrier();
  __builtin_amdgcn_sched_barrier(0);

  // Main loop: tiles 0..89 (96 total at BK=32); buf = T%3, stage T+2.
  for (int T = 0; T < 90; T += 3) {
    TILE3(0, 2, T + 2, 1, VMB(), 1);
    TILE3(1, 0, T + 3, 1, VMB(), 1);
    TILE3(2, 1, T + 4, 1, VMB(), 1);
  }
  // Tiles 90..95: stages run out at 95; drain at 94.
  TILE3(0, 2, 92, 1, VMB(), 1);   // tile 90
  TILE3(1, 0, 93, 1, VMB(), 1);   // tile 91
  TILE3(2, 1, 94, 1, VMB(), 1);   // tile 92
  TILE3(0, 2, 95, 1, VMB(), 1);   // tile 93
  TILE3(1, 2, 0,  0, VM0(), 1);   // tile 94 (no stage; force 95's loads)
  TILE3(2, 2, 0,  0, (void)0, 0); // tile 95 (no stage, no barrier)

  // ---- lora epilogue: acc += lora_act(256x32) . proj_up(192x32)^T (L2-hot) ----
  bf16x8 bl[6];
#pragma unroll
  for (int bb = 0; bb < 6; ++bb) {
    const int bcol = n0 + (bb / 3) * 96 + wn * 48 + (bb % 3) * 16 + lm;
    bl[bb] = *(const bf16x8*)(pu_bf + (size_t)bcol * RANK + q4 * 8);
  }
#pragma unroll
  for (int a = 0; a < 4; ++a) {
    const int arow = m0 + (a >> 1) * 128 + wm * 32 + (a & 1) * 16 + lm;
    const bf16x8 al = *(const bf16x8*)(lora_bf + (size_t)arow * RANK + q4 * 8);
#pragma unroll
    for (int bb = 0; bb < 6; ++bb)
      acc[a][bb] = __builtin_amdgcn_mfma_f32_16x16x32_bf16(al, bl[bb], acc[a][bb], 0, 0, 0);
  }

  // store: C/D layout col=lane&15, row=(lane>>4)*4+reg  [m89-verified]
#pragma unroll
  for (int bb = 0; bb < 6; ++bb) {
    const int col = n0 + (bb / 3) * 96 + wn * 48 + (bb % 3) * 16 + lm;
    const float bv = bias[col];
#pragma unroll
    for (int a = 0; a < 4; ++a) {
      const int row0 = m0 + (a >> 1) * 128 + wm * 32 + (a & 1) * 16 + q4 * 4;
#pragma unroll
      for (int r = 0; r < 4; ++r)
        out[(size_t)(row0 + r) * COUT + col] = acc[a][bb][r] + bv;
    }
  }
}

extern "C" void kernel_launch(void* const* d_in, const int* in_sizes, int n_in,
                              void* d_out, int out_size, void* d_ws, size_t ws_size,
                              hipStream_t stream) {
  const float* x      = (const float*)d_in[0];
  const int*   qw     = (const int*)d_in[1];
  const float* wsc    = (const float*)d_in[2];
  const float* smooth = (const float*)d_in[3];
  const float* pd     = (const float*)d_in[4];
  const float* pu     = (const float*)d_in[5];
  const float* bias   = (const float*)d_in[6];
  float* out = (float*)d_out;

  u16* xdq     = (u16*)d_ws;                               // 4096*3136*2 = 25.7 MB
  u16* wdq     = xdq + (size_t)MTOK * RS;                  // 3072*3136*2 = 19.3 MB
  u16* pu_bf   = wdq + (size_t)COUT * RS;                  // 3072*32*2   = 0.2 MB
  u16* lora_bf = pu_bf + (size_t)COUT * RANK;              // 4096*32*2   = 0.3 MB
  float* lp    = (float*)(lora_bf + (size_t)MTOK * RANK);  // 16*4096*32*4 = 8.4 MB

  prep_kernel<<<512, 256, 0, stream>>>(
      x, smooth, qw, wsc, pd, pu, xdq, wdq, pu_bf, lp);
  lora_fix_kernel<<<MTOK * RANK / 256, 256, 0, stream>>>(lp, lora_bf);
  gemm_kernel<<<256, 512, 0, stream>>>(
      xdq, wdq, pu_bf, lora_bf, bias, out);
}